// Round 1
// baseline (1643.555 us; speedup 1.0000x reference)
//
#include <hip/hip_runtime.h>
#include <cmath>
#include <cstddef>

namespace {

constexpr int cB = 2, cL = 2048, cS = 2048, cD = 1024, cH = 16, cNS = 8, cNSLOT = 512, cHD = 64;

__device__ __forceinline__ float sigmoidf_(float x) { return 1.f / (1.f + __expf(-x)); }

// XOR swizzle of float4 groups within a 64-float row (breaks row-stride bank aliasing)
__device__ __forceinline__ int swz(int row, int col) {
  return ((((col >> 2) ^ (row & 15)) & 15) << 2) | (col & 3);
}

// ---------------- LayerNorm of E_slots rows ----------------
__global__ __launch_bounds__(256) void ln_slots_kernel(const float* __restrict__ E,
                                                       const float* __restrict__ gamma,
                                                       const float* __restrict__ beta,
                                                       float* __restrict__ out) {
  __shared__ float rbuf[8];
  const int row = blockIdx.x;
  const int tid = threadIdx.x;
  const int d0 = tid * 4;
  const float4 x = *(const float4*)(E + (size_t)row * cD + d0);
  float s1 = x.x + x.y + x.z + x.w;
  float s2 = x.x * x.x + x.y * x.y + x.z * x.z + x.w * x.w;
#pragma unroll
  for (int o = 32; o > 0; o >>= 1) { s1 += __shfl_xor(s1, o, 64); s2 += __shfl_xor(s2, o, 64); }
  if ((tid & 63) == 0) { rbuf[tid >> 6] = s1; rbuf[4 + (tid >> 6)] = s2; }
  __syncthreads();
  s1 = rbuf[0] + rbuf[1] + rbuf[2] + rbuf[3];
  s2 = rbuf[4] + rbuf[5] + rbuf[6] + rbuf[7];
  const float mean = s1 * (1.f / cD);
  const float var = s2 * (1.f / cD) - mean * mean;
  const float inv = rsqrtf(var + 1e-5f);
  const float4 g = *(const float4*)(gamma + d0);
  const float4 b = *(const float4*)(beta + d0);
  float4 y;
  y.x = (x.x - mean) * inv * g.x + b.x;
  y.y = (x.y - mean) * inv * g.y + b.y;
  y.z = (x.z - mean) * inv * g.z + b.z;
  y.w = (x.w - mean) * inv * g.w + b.w;
  *(float4*)(out + (size_t)row * cD + d0) = y;
}

// ---------------- Q-side: Y = LN(x_q * SiLU(C_seq @ Wpe^T)) ----------------
__global__ __launch_bounds__(256) void qgate_ln_kernel(const float* __restrict__ xq,
                                                       const float* __restrict__ Cseq,
                                                       const float* __restrict__ Wpe,
                                                       const float* __restrict__ gamma,
                                                       const float* __restrict__ beta,
                                                       float* __restrict__ Y) {
  __shared__ float sC[cNS];
  __shared__ float rbuf[8];
  const int row = blockIdx.x;  // b*L + l
  const int tid = threadIdx.x;
  if (tid < cNS) sC[tid] = Cseq[(size_t)row * cNS + tid];
  __syncthreads();
  const int d0 = tid * 4;
  const float4 x = *(const float4*)(xq + (size_t)row * cD + d0);
  float y[4];
  float s1 = 0.f, s2 = 0.f;
#pragma unroll
  for (int j = 0; j < 4; j++) {
    const float* wr = Wpe + (size_t)(d0 + j) * cNS;
    float gs = 0.f;
#pragma unroll
    for (int m = 0; m < cNS; m++) gs += sC[m] * wr[m];
    const float val = ((const float*)&x)[j] * gs * sigmoidf_(gs);
    y[j] = val;
    s1 += val;
    s2 += val * val;
  }
#pragma unroll
  for (int o = 32; o > 0; o >>= 1) { s1 += __shfl_xor(s1, o, 64); s2 += __shfl_xor(s2, o, 64); }
  if ((tid & 63) == 0) { rbuf[tid >> 6] = s1; rbuf[4 + (tid >> 6)] = s2; }
  __syncthreads();
  s1 = rbuf[0] + rbuf[1] + rbuf[2] + rbuf[3];
  s2 = rbuf[4] + rbuf[5] + rbuf[6] + rbuf[7];
  const float mean = s1 * (1.f / cD);
  const float var = s2 * (1.f / cD) - mean * mean;
  const float inv = rsqrtf(var + 1e-5f);
  const float4 g = *(const float4*)(gamma + d0);
  const float4 b = *(const float4*)(beta + d0);
  float4 o4;
  o4.x = (y[0] - mean) * inv * g.x + b.x;
  o4.y = (y[1] - mean) * inv * g.y + b.y;
  o4.z = (y[2] - mean) * inv * g.z + b.z;
  o4.w = (y[3] - mean) * inv * g.w + b.w;
  *(float4*)(Y + (size_t)row * cD + d0) = o4;
}

// ---------------- gate_kv[s, d] = SiLU( sum_m rho_m^(S-1-s) * Wpe[d, m] ) ----------------
__global__ __launch_bounds__(256) void gatekv_kernel(const float* __restrict__ rhos,
                                                     const float* __restrict__ Wpe,
                                                     float* __restrict__ gkv) {
  __shared__ float sC[cNS];
  const int s = blockIdx.x;
  const int tid = threadIdx.x;
  if (tid < cNS) {
    const float age = (float)(cS - 1 - s);
    sC[tid] = __expf(age * __logf(rhos[tid]));
  }
  __syncthreads();
  const int d0 = tid * 4;
  float4 o4;
#pragma unroll
  for (int j = 0; j < 4; j++) {
    const float* wr = Wpe + (size_t)(d0 + j) * cNS;
    float gs = 0.f;
#pragma unroll
    for (int m = 0; m < cNS; m++) gs += sC[m] * wr[m];
    ((float*)&o4)[j] = gs * sigmoidf_(gs);
  }
  *(float4*)(gkv + (size_t)s * cD + d0) = o4;
}

// ---------------- fp32 GEMM: C[M,N] = A[M,K] @ W[N,K]^T ----------------
// 128x128 tile, BK=16, 256 threads, 8x8 accumulators per thread.
__global__ __launch_bounds__(256) void gemm_nt_kernel(const float* __restrict__ A,
                                                      const float* __restrict__ W,
                                                      float* __restrict__ C,
                                                      int M, int N, int K) {
  __shared__ float sA[16][132];
  __shared__ float sB[16][132];
  const int tid = threadIdx.x;
  const int m0 = blockIdx.y * 128;
  const int n0 = blockIdx.x * 128;
  const int tx = tid & 15;   // n-direction
  const int ty = tid >> 4;   // m-direction
  float acc[8][8];
#pragma unroll
  for (int i = 0; i < 8; i++)
#pragma unroll
    for (int j = 0; j < 8; j++) acc[i][j] = 0.f;

  const int lr = tid >> 1;        // 0..127 tile row for staging
  const int lc = (tid & 1) * 8;   // 0 or 8 within BK
  const float* Aptr = A + (size_t)(m0 + lr) * K + lc;
  const float* Wptr = W + (size_t)(n0 + lr) * K + lc;

  for (int k0 = 0; k0 < K; k0 += 16) {
    const float4 a0 = *(const float4*)(Aptr + k0);
    const float4 a1 = *(const float4*)(Aptr + k0 + 4);
    const float4 b0 = *(const float4*)(Wptr + k0);
    const float4 b1 = *(const float4*)(Wptr + k0 + 4);
    __syncthreads();
    sA[lc + 0][lr] = a0.x; sA[lc + 1][lr] = a0.y; sA[lc + 2][lr] = a0.z; sA[lc + 3][lr] = a0.w;
    sA[lc + 4][lr] = a1.x; sA[lc + 5][lr] = a1.y; sA[lc + 6][lr] = a1.z; sA[lc + 7][lr] = a1.w;
    sB[lc + 0][lr] = b0.x; sB[lc + 1][lr] = b0.y; sB[lc + 2][lr] = b0.z; sB[lc + 3][lr] = b0.w;
    sB[lc + 4][lr] = b1.x; sB[lc + 5][lr] = b1.y; sB[lc + 6][lr] = b1.z; sB[lc + 7][lr] = b1.w;
    __syncthreads();
#pragma unroll
    for (int kk = 0; kk < 16; kk++) {
      const float4 av0 = *(const float4*)&sA[kk][ty * 8];
      const float4 av1 = *(const float4*)&sA[kk][ty * 8 + 4];
      const float4 bv0 = *(const float4*)&sB[kk][tx * 8];
      const float4 bv1 = *(const float4*)&sB[kk][tx * 8 + 4];
      const float am[8] = {av0.x, av0.y, av0.z, av0.w, av1.x, av1.y, av1.z, av1.w};
      const float bn[8] = {bv0.x, bv0.y, bv0.z, bv0.w, bv1.x, bv1.y, bv1.z, bv1.w};
#pragma unroll
      for (int i = 0; i < 8; i++)
#pragma unroll
        for (int j = 0; j < 8; j++) acc[i][j] += am[i] * bn[j];
    }
  }
#pragma unroll
  for (int i = 0; i < 8; i++) {
    const size_t m = (size_t)(m0 + ty * 8 + i);
    float4 c0 = make_float4(acc[i][0], acc[i][1], acc[i][2], acc[i][3]);
    float4 c1 = make_float4(acc[i][4], acc[i][5], acc[i][6], acc[i][7]);
    *(float4*)(C + m * N + n0 + tx * 8) = c0;
    *(float4*)(C + m * N + n0 + tx * 8 + 4) = c1;
  }
}

// ---------------- flash attention, fused K/V gather+gate ----------------
// block: (l-tile of 32) x head x batch, 256 threads. s-chunk = 64.
__global__ __launch_bounds__(256) void attn_kernel(const float* __restrict__ Q,
                                                   const float* __restrict__ Ek,
                                                   const float* __restrict__ Ev,
                                                   const float* __restrict__ gkv,
                                                   const int* __restrict__ xidx,
                                                   float* __restrict__ AO) {
  __shared__ float sQ[32 * 68];
  __shared__ float sK[64 * 64];
  __shared__ float sV[64 * 64];
  __shared__ float sP[32 * 68];
  const int lt = blockIdx.x * 32;
  const int h = blockIdx.y;
  const int b = blockIdx.z;
  const int tid = threadIdx.x;
  // stage Q tile [32 x 64]
  {
    const int r = tid >> 3;
    const int c = (tid & 7) * 8;
    const float* src = Q + (size_t)(b * cL + lt + r) * cD + h * cHD + c;
    *(float4*)&sQ[r * 68 + c] = *(const float4*)src;
    *(float4*)&sQ[r * 68 + c + 4] = *(const float4*)(src + 4);
  }
  const int tx = tid & 15;
  const int tyq = tid >> 4;
  const int l0 = tyq * 2, l1 = l0 + 1;
  float m0 = -INFINITY, m1 = -INFINITY, den0 = 0.f, den1 = 0.f;
  float o0[4] = {0.f, 0.f, 0.f, 0.f}, o1[4] = {0.f, 0.f, 0.f, 0.f};
  const int sr = tid >> 2;        // 0..63 staging row
  const int cb = (tid & 3) * 16;  // staging col base
  constexpr float scale = 0.125f; // 1/sqrt(64)

  for (int s0 = 0; s0 < cS; s0 += 64) {
    // fused gather+gate staging of K/V chunk [64 x 64]
    const int sidx = s0 + sr;
    const int slot = xidx[b * cS + sidx];
    const float* ekp = Ek + (size_t)slot * cD + h * cHD + cb;
    const float* evp = Ev + (size_t)slot * cD + h * cHD + cb;
    const float* gp = gkv + (size_t)sidx * cD + h * cHD + cb;
    float4 kreg[4], vreg[4];
#pragma unroll
    for (int q = 0; q < 4; q++) {
      float4 g4 = *(const float4*)(gp + q * 4);
      float4 k4 = *(const float4*)(ekp + q * 4);
      float4 v4 = *(const float4*)(evp + q * 4);
      k4.x *= g4.x; k4.y *= g4.y; k4.z *= g4.z; k4.w *= g4.w;
      v4.x *= g4.x; v4.y *= g4.y; v4.z *= g4.z; v4.w *= g4.w;
      kreg[q] = k4;
      vreg[q] = v4;
    }
    __syncthreads();  // prior iteration done with sK/sV/sP
#pragma unroll
    for (int q = 0; q < 4; q++) {
      const int c = cb + q * 4;
      *(float4*)&sK[sr * 64 + swz(sr, c)] = kreg[q];
      *(float4*)&sV[sr * 64 + swz(sr, c)] = vreg[q];
    }
    __syncthreads();
    // QK^T: thread computes scores for rows l0,l1 and s = tx*4..tx*4+3
    float sc0[4] = {0.f, 0.f, 0.f, 0.f}, sc1[4] = {0.f, 0.f, 0.f, 0.f};
#pragma unroll
    for (int hd = 0; hd < cHD; hd += 4) {
      const float4 qa = *(const float4*)&sQ[l0 * 68 + hd];
      const float4 qb = *(const float4*)&sQ[l1 * 68 + hd];
#pragma unroll
      for (int j = 0; j < 4; j++) {
        const int s = tx * 4 + j;
        const float4 kv = *(const float4*)&sK[s * 64 + swz(s, hd)];
        sc0[j] += qa.x * kv.x + qa.y * kv.y + qa.z * kv.z + qa.w * kv.w;
        sc1[j] += qb.x * kv.x + qb.y * kv.y + qb.z * kv.z + qb.w * kv.w;
      }
    }
    float mx0 = -INFINITY, mx1 = -INFINITY;
#pragma unroll
    for (int j = 0; j < 4; j++) {
      sc0[j] *= scale;
      sc1[j] *= scale;
      mx0 = fmaxf(mx0, sc0[j]);
      mx1 = fmaxf(mx1, sc1[j]);
    }
#pragma unroll
    for (int o = 1; o < 16; o <<= 1) {
      mx0 = fmaxf(mx0, __shfl_xor(mx0, o, 64));
      mx1 = fmaxf(mx1, __shfl_xor(mx1, o, 64));
    }
    const float mn0 = fmaxf(m0, mx0), mn1 = fmaxf(m1, mx1);
    const float al0 = __expf(m0 - mn0), al1 = __expf(m1 - mn1);
    float p0[4], p1[4];
    float ps0 = 0.f, ps1 = 0.f;
#pragma unroll
    for (int j = 0; j < 4; j++) {
      p0[j] = __expf(sc0[j] - mn0); ps0 += p0[j];
      p1[j] = __expf(sc1[j] - mn1); ps1 += p1[j];
    }
#pragma unroll
    for (int o = 1; o < 16; o <<= 1) {
      ps0 += __shfl_xor(ps0, o, 64);
      ps1 += __shfl_xor(ps1, o, 64);
    }
    den0 = den0 * al0 + ps0;
    den1 = den1 * al1 + ps1;
    m0 = mn0;
    m1 = mn1;
    *(float4*)&sP[l0 * 68 + tx * 4] = make_float4(p0[0], p0[1], p0[2], p0[3]);
    *(float4*)&sP[l1 * 68 + tx * 4] = make_float4(p1[0], p1[1], p1[2], p1[3]);
#pragma unroll
    for (int i = 0; i < 4; i++) { o0[i] *= al0; o1[i] *= al1; }
    __syncthreads();
    // PV: O[l][tx*4..+3] += sum_s P[l][s] * V[s][tx*4..+3]
#pragma unroll
    for (int s4 = 0; s4 < 64; s4 += 4) {
      const float4 pa = *(const float4*)&sP[l0 * 68 + s4];
      const float4 pb = *(const float4*)&sP[l1 * 68 + s4];
#pragma unroll
      for (int j = 0; j < 4; j++) {
        const int s = s4 + j;
        const float4 vv = *(const float4*)&sV[s * 64 + swz(s, tx * 4)];
        const float pj0 = ((const float*)&pa)[j];
        const float pj1 = ((const float*)&pb)[j];
        o0[0] += pj0 * vv.x; o0[1] += pj0 * vv.y; o0[2] += pj0 * vv.z; o0[3] += pj0 * vv.w;
        o1[0] += pj1 * vv.x; o1[1] += pj1 * vv.y; o1[2] += pj1 * vv.z; o1[3] += pj1 * vv.w;
      }
    }
  }
  const float i0 = 1.f / den0, i1 = 1.f / den1;
  const float4 w0 = make_float4(o0[0] * i0, o0[1] * i0, o0[2] * i0, o0[3] * i0);
  const float4 w1 = make_float4(o1[0] * i1, o1[1] * i1, o1[2] * i1, o1[3] * i1);
  *(float4*)(AO + (size_t)(b * cL + lt + l0) * cD + h * cHD + tx * 4) = w0;
  *(float4*)(AO + (size_t)(b * cL + lt + l1) * cD + h * cHD + tx * 4) = w1;
}

}  // namespace

extern "C" void kernel_launch(void* const* d_in, const int* in_sizes, int n_in,
                              void* d_out, int out_size, void* d_ws, size_t ws_size,
                              hipStream_t stream) {
  (void)in_sizes; (void)n_in; (void)out_size; (void)ws_size;
  const float* x_q = (const float*)d_in[0];
  const int* x_idx = (const int*)d_in[1];
  const float* E_slots = (const float*)d_in[2];
  const float* rhos = (const float*)d_in[3];
  const float* C_seq = (const float*)d_in[4];
  const float* Wq = (const float*)d_in[5];
  const float* Wk = (const float*)d_in[6];
  const float* Wv = (const float*)d_in[7];
  const float* Wo = (const float*)d_in[8];
  const float* Wpe = (const float*)d_in[9];
  const float* ln_kv_g = (const float*)d_in[10];
  const float* ln_kv_b = (const float*)d_in[11];
  const float* ln_q_g = (const float*)d_in[12];
  const float* ln_q_b = (const float*)d_in[13];
  float* out = (float*)d_out;

  float* ws = (float*)d_ws;
  float* mem = ws;                               // NSLOT*D      = 0.5M floats
  float* Ek = mem + (size_t)cNSLOT * cD;         // NSLOT*D
  float* Ev = Ek + (size_t)cNSLOT * cD;          // NSLOT*D
  float* gkv = Ev + (size_t)cNSLOT * cD;         // S*D          = 2M floats
  float* Y = gkv + (size_t)cS * cD;              // B*L*D        = 4M floats
  float* Qb = Y + (size_t)cB * cL * cD;          // B*L*D        = 4M floats
  float* AO = Y;                                 // alias: Y dead after Q projection
  // total ws: 11.5M floats = 46 MB

  ln_slots_kernel<<<cNSLOT, 256, 0, stream>>>(E_slots, ln_kv_g, ln_kv_b, mem);
  gemm_nt_kernel<<<dim3(cD / 128, cNSLOT / 128), 256, 0, stream>>>(mem, Wk, Ek, cNSLOT, cD, cD);
  gemm_nt_kernel<<<dim3(cD / 128, cNSLOT / 128), 256, 0, stream>>>(mem, Wv, Ev, cNSLOT, cD, cD);
  gatekv_kernel<<<cS, 256, 0, stream>>>(rhos, Wpe, gkv);
  qgate_ln_kernel<<<cB * cL, 256, 0, stream>>>(x_q, C_seq, Wpe, ln_q_g, ln_q_b, Y);
  gemm_nt_kernel<<<dim3(cD / 128, (cB * cL) / 128), 256, 0, stream>>>(Y, Wq, Qb, cB * cL, cD, cD);
  attn_kernel<<<dim3(cL / 32, cH, cB), 256, 0, stream>>>(Qb, Ek, Ev, gkv, x_idx, AO);
  gemm_nt_kernel<<<dim3(cD / 128, (cB * cL) / 128), 256, 0, stream>>>(AO, Wo, out, cB * cL, cD, cD);
}

// Round 2
// 863.126 us; speedup vs baseline: 1.9042x; 1.9042x over previous
//
#include <hip/hip_runtime.h>
#include <cmath>
#include <cstddef>

namespace {

constexpr int cB = 2, cL = 2048, cS = 2048, cD = 1024, cH = 16, cNS = 8, cNSLOT = 512, cHD = 64;

typedef __attribute__((ext_vector_type(8))) short short8;
typedef __attribute__((ext_vector_type(4))) float f32x4;

#define MFMA16(a, b, c) __builtin_amdgcn_mfma_f32_16x16x32_bf16((a), (b), (c), 0, 0, 0)

__device__ __forceinline__ float sigmoidf_(float x) { return 1.f / (1.f + __expf(-x)); }

__device__ __forceinline__ unsigned short f2bf(float x) {
  union { float f; unsigned u; } c; c.f = x;
  unsigned r = c.u + 0x7FFFu + ((c.u >> 16) & 1u);
  return (unsigned short)(r >> 16);
}
__device__ __forceinline__ float bf2f(unsigned short h) {
  union { unsigned u; float f; } c; c.u = ((unsigned)h) << 16;
  return c.f;
}

// ---------------- LayerNorm of E_slots rows ----------------
__global__ __launch_bounds__(256) void ln_slots_kernel(const float* __restrict__ E,
                                                       const float* __restrict__ gamma,
                                                       const float* __restrict__ beta,
                                                       float* __restrict__ out) {
  __shared__ float rbuf[8];
  const int row = blockIdx.x;
  const int tid = threadIdx.x;
  const int d0 = tid * 4;
  const float4 x = *(const float4*)(E + (size_t)row * cD + d0);
  float s1 = x.x + x.y + x.z + x.w;
  float s2 = x.x * x.x + x.y * x.y + x.z * x.z + x.w * x.w;
#pragma unroll
  for (int o = 32; o > 0; o >>= 1) { s1 += __shfl_xor(s1, o, 64); s2 += __shfl_xor(s2, o, 64); }
  if ((tid & 63) == 0) { rbuf[tid >> 6] = s1; rbuf[4 + (tid >> 6)] = s2; }
  __syncthreads();
  s1 = rbuf[0] + rbuf[1] + rbuf[2] + rbuf[3];
  s2 = rbuf[4] + rbuf[5] + rbuf[6] + rbuf[7];
  const float mean = s1 * (1.f / cD);
  const float var = s2 * (1.f / cD) - mean * mean;
  const float inv = rsqrtf(var + 1e-5f);
  const float4 g = *(const float4*)(gamma + d0);
  const float4 b = *(const float4*)(beta + d0);
  float4 y;
  y.x = (x.x - mean) * inv * g.x + b.x;
  y.y = (x.y - mean) * inv * g.y + b.y;
  y.z = (x.z - mean) * inv * g.z + b.z;
  y.w = (x.w - mean) * inv * g.w + b.w;
  *(float4*)(out + (size_t)row * cD + d0) = y;
}

// ---------------- Q-side: Y = LN(x_q * SiLU(C_seq @ Wpe^T)) ----------------
__global__ __launch_bounds__(256) void qgate_ln_kernel(const float* __restrict__ xq,
                                                       const float* __restrict__ Cseq,
                                                       const float* __restrict__ Wpe,
                                                       const float* __restrict__ gamma,
                                                       const float* __restrict__ beta,
                                                       float* __restrict__ Y) {
  __shared__ float sC[cNS];
  __shared__ float rbuf[8];
  const int row = blockIdx.x;
  const int tid = threadIdx.x;
  if (tid < cNS) sC[tid] = Cseq[(size_t)row * cNS + tid];
  __syncthreads();
  const int d0 = tid * 4;
  const float4 x = *(const float4*)(xq + (size_t)row * cD + d0);
  float y[4];
  float s1 = 0.f, s2 = 0.f;
#pragma unroll
  for (int j = 0; j < 4; j++) {
    const float* wr = Wpe + (size_t)(d0 + j) * cNS;
    float gs = 0.f;
#pragma unroll
    for (int m = 0; m < cNS; m++) gs += sC[m] * wr[m];
    const float val = ((const float*)&x)[j] * gs * sigmoidf_(gs);
    y[j] = val;
    s1 += val;
    s2 += val * val;
  }
#pragma unroll
  for (int o = 32; o > 0; o >>= 1) { s1 += __shfl_xor(s1, o, 64); s2 += __shfl_xor(s2, o, 64); }
  if ((tid & 63) == 0) { rbuf[tid >> 6] = s1; rbuf[4 + (tid >> 6)] = s2; }
  __syncthreads();
  s1 = rbuf[0] + rbuf[1] + rbuf[2] + rbuf[3];
  s2 = rbuf[4] + rbuf[5] + rbuf[6] + rbuf[7];
  const float mean = s1 * (1.f / cD);
  const float var = s2 * (1.f / cD) - mean * mean;
  const float inv = rsqrtf(var + 1e-5f);
  const float4 g = *(const float4*)(gamma + d0);
  const float4 b = *(const float4*)(beta + d0);
  float4 o4;
  o4.x = (y[0] - mean) * inv * g.x + b.x;
  o4.y = (y[1] - mean) * inv * g.y + b.y;
  o4.z = (y[2] - mean) * inv * g.z + b.z;
  o4.w = (y[3] - mean) * inv * g.w + b.w;
  *(float4*)(Y + (size_t)row * cD + d0) = o4;
}

// ---------------- gate_kv[s, d] = SiLU( sum_m rho_m^(S-1-s) * Wpe[d, m] ) ----------------
__global__ __launch_bounds__(256) void gatekv_kernel(const float* __restrict__ rhos,
                                                     const float* __restrict__ Wpe,
                                                     float* __restrict__ gkv) {
  __shared__ float sC[cNS];
  const int s = blockIdx.x;
  const int tid = threadIdx.x;
  if (tid < cNS) {
    const float age = (float)(cS - 1 - s);
    sC[tid] = __expf(age * __logf(rhos[tid]));
  }
  __syncthreads();
  const int d0 = tid * 4;
  float4 o4;
#pragma unroll
  for (int j = 0; j < 4; j++) {
    const float* wr = Wpe + (size_t)(d0 + j) * cNS;
    float gs = 0.f;
#pragma unroll
    for (int m = 0; m < cNS; m++) gs += sC[m] * wr[m];
    ((float*)&o4)[j] = gs * sigmoidf_(gs);
  }
  *(float4*)(gkv + (size_t)s * cD + d0) = o4;
}

// ---------------- fp32 GEMM: C[M,N] = A[M,K] @ W[N,K]^T ----------------
__global__ __launch_bounds__(256) void gemm_nt_kernel(const float* __restrict__ A,
                                                      const float* __restrict__ W,
                                                      float* __restrict__ C,
                                                      int M, int N, int K) {
  __shared__ float sA[16][132];
  __shared__ float sB[16][132];
  const int tid = threadIdx.x;
  const int m0 = blockIdx.y * 128;
  const int n0 = blockIdx.x * 128;
  const int tx = tid & 15;
  const int ty = tid >> 4;
  float acc[8][8];
#pragma unroll
  for (int i = 0; i < 8; i++)
#pragma unroll
    for (int j = 0; j < 8; j++) acc[i][j] = 0.f;

  const int lr = tid >> 1;
  const int lc = (tid & 1) * 8;
  const float* Aptr = A + (size_t)(m0 + lr) * K + lc;
  const float* Wptr = W + (size_t)(n0 + lr) * K + lc;

  for (int k0 = 0; k0 < K; k0 += 16) {
    const float4 a0 = *(const float4*)(Aptr + k0);
    const float4 a1 = *(const float4*)(Aptr + k0 + 4);
    const float4 b0 = *(const float4*)(Wptr + k0);
    const float4 b1 = *(const float4*)(Wptr + k0 + 4);
    __syncthreads();
    sA[lc + 0][lr] = a0.x; sA[lc + 1][lr] = a0.y; sA[lc + 2][lr] = a0.z; sA[lc + 3][lr] = a0.w;
    sA[lc + 4][lr] = a1.x; sA[lc + 5][lr] = a1.y; sA[lc + 6][lr] = a1.z; sA[lc + 7][lr] = a1.w;
    sB[lc + 0][lr] = b0.x; sB[lc + 1][lr] = b0.y; sB[lc + 2][lr] = b0.z; sB[lc + 3][lr] = b0.w;
    sB[lc + 4][lr] = b1.x; sB[lc + 5][lr] = b1.y; sB[lc + 6][lr] = b1.z; sB[lc + 7][lr] = b1.w;
    __syncthreads();
#pragma unroll
    for (int kk = 0; kk < 16; kk++) {
      const float4 av0 = *(const float4*)&sA[kk][ty * 8];
      const float4 av1 = *(const float4*)&sA[kk][ty * 8 + 4];
      const float4 bv0 = *(const float4*)&sB[kk][tx * 8];
      const float4 bv1 = *(const float4*)&sB[kk][tx * 8 + 4];
      const float am[8] = {av0.x, av0.y, av0.z, av0.w, av1.x, av1.y, av1.z, av1.w};
      const float bn[8] = {bv0.x, bv0.y, bv0.z, bv0.w, bv1.x, bv1.y, bv1.z, bv1.w};
#pragma unroll
      for (int i = 0; i < 8; i++)
#pragma unroll
        for (int j = 0; j < 8; j++) acc[i][j] += am[i] * bn[j];
    }
  }
#pragma unroll
  for (int i = 0; i < 8; i++) {
    const size_t m = (size_t)(m0 + ty * 8 + i);
    float4 c0 = make_float4(acc[i][0], acc[i][1], acc[i][2], acc[i][3]);
    float4 c1 = make_float4(acc[i][4], acc[i][5], acc[i][6], acc[i][7]);
    *(float4*)(C + m * N + n0 + tx * 8) = c0;
    *(float4*)(C + m * N + n0 + tx * 8 + 4) = c1;
  }
}

// ---------------- prep: K = gather(Ek)·gate, split hi/lo bf16, row-major [B][S][D] ----------------
__global__ __launch_bounds__(256) void prep_k_kernel(const float* __restrict__ Ek,
                                                     const float* __restrict__ gkv,
                                                     const int* __restrict__ xidx,
                                                     unsigned short* __restrict__ Khi,
                                                     unsigned short* __restrict__ Klo) {
  const int t = blockIdx.x * 256 + threadIdx.x;
  const int d0 = (t & 127) * 8;
  const int s = (t >> 7) & (cS - 1);
  const int b = t >> 18;
  const int slot = xidx[b * cS + s];
  const float4 e0 = *(const float4*)(Ek + (size_t)slot * cD + d0);
  const float4 e1 = *(const float4*)(Ek + (size_t)slot * cD + d0 + 4);
  const float4 g0 = *(const float4*)(gkv + (size_t)s * cD + d0);
  const float4 g1 = *(const float4*)(gkv + (size_t)s * cD + d0 + 4);
  float v[8] = {e0.x * g0.x, e0.y * g0.y, e0.z * g0.z, e0.w * g0.w,
                e1.x * g1.x, e1.y * g1.y, e1.z * g1.z, e1.w * g1.w};
  unsigned short h8[8], l8[8];
#pragma unroll
  for (int j = 0; j < 8; j++) {
    h8[j] = f2bf(v[j]);
    l8[j] = f2bf(v[j] - bf2f(h8[j]));
  }
  const size_t off = (size_t)(b * cS + s) * cD + d0;
  *(uint4*)(Khi + off) = *(uint4*)h8;
  *(uint4*)(Klo + off) = *(uint4*)l8;
}

// ---------------- prep: Vt[b][d][s] = gather(Ev)·gate, split hi/lo bf16 (transposed) ----------------
__global__ __launch_bounds__(256) void prep_vt_kernel(const float* __restrict__ Ev,
                                                      const float* __restrict__ gkv,
                                                      const int* __restrict__ xidx,
                                                      unsigned short* __restrict__ Vthi,
                                                      unsigned short* __restrict__ Vtlo) {
  __shared__ float tile[64][65];
  const int s0 = blockIdx.x * 64, d0 = blockIdx.y * 64, b = blockIdx.z;
  const int tid = threadIdx.x;
  const int sl = tid >> 4;
  const int dl = (tid & 15) * 4;
#pragma unroll
  for (int it = 0; it < 4; it++) {
    const int s = s0 + sl + it * 16;
    const int slot = xidx[b * cS + s];
    const float4 e = *(const float4*)(Ev + (size_t)slot * cD + d0 + dl);
    const float4 g = *(const float4*)(gkv + (size_t)s * cD + d0 + dl);
    tile[sl + it * 16][dl + 0] = e.x * g.x;
    tile[sl + it * 16][dl + 1] = e.y * g.y;
    tile[sl + it * 16][dl + 2] = e.z * g.z;
    tile[sl + it * 16][dl + 3] = e.w * g.w;
  }
  __syncthreads();
  const int dr = tid >> 3;
  const int sc = (tid & 7) * 8;
#pragma unroll
  for (int it = 0; it < 2; it++) {
    const int d = d0 + dr + it * 32;
    unsigned short h8[8], l8[8];
#pragma unroll
    for (int j = 0; j < 8; j++) {
      const float v = tile[sc + j][dr + it * 32];
      h8[j] = f2bf(v);
      l8[j] = f2bf(v - bf2f(h8[j]));
    }
    const size_t off = (size_t)(b * cD + d) * cS + s0 + sc;
    *(uint4*)(Vthi + off) = *(uint4*)h8;
    *(uint4*)(Vtlo + off) = *(uint4*)l8;
  }
}

// ---------------- prep: q = Qb*0.125 split hi/lo bf16 ----------------
__global__ __launch_bounds__(256) void prep_q_kernel(const float* __restrict__ Qb,
                                                     unsigned short* __restrict__ qhi,
                                                     unsigned short* __restrict__ qlo) {
  const size_t t = (size_t)blockIdx.x * 256 + threadIdx.x;
  const size_t off = t * 8;
  const float4 a = *(const float4*)(Qb + off);
  const float4 b4 = *(const float4*)(Qb + off + 4);
  float v[8] = {a.x, a.y, a.z, a.w, b4.x, b4.y, b4.z, b4.w};
  unsigned short h8[8], l8[8];
#pragma unroll
  for (int j = 0; j < 8; j++) {
    const float s = v[j] * 0.125f;
    h8[j] = f2bf(s);
    l8[j] = f2bf(s - bf2f(h8[j]));
  }
  *(uint4*)(qhi + off) = *(uint4*)h8;
  *(uint4*)(qlo + off) = *(uint4*)l8;
}

// ---------------- MFMA flash attention, hi/lo split Q,K,P,V ----------------
// grid (L/128, H, B), 256 threads = 4 waves. Wave owns 32 l-rows (2 bands of 16).
// s-chunk = 32 (2 16-wide s-tiles).
__global__ __launch_bounds__(256, 3) void attn_mfma_kernel(
    const unsigned short* __restrict__ qhi, const unsigned short* __restrict__ qlo,
    const unsigned short* __restrict__ Khi, const unsigned short* __restrict__ Klo,
    const unsigned short* __restrict__ Vthi, const unsigned short* __restrict__ Vtlo,
    float* __restrict__ AO) {
  __shared__ __align__(16) unsigned short sKhi[32][72];
  __shared__ __align__(16) unsigned short sKlo[32][72];
  __shared__ __align__(16) unsigned short sVhi[64][40];
  __shared__ __align__(16) unsigned short sVlo[64][40];
  __shared__ __align__(16) unsigned short sP[4][2][2][16][40];  // [wave][band][hi/lo][l][s]

  const int tid = threadIdx.x;
  const int wave = tid >> 6, lane = tid & 63;
  const int quad = lane >> 4, l16 = lane & 15;
  const int lB = blockIdx.x * 128;
  const int h = blockIdx.y, b = blockIdx.z;

  // Q fragments in registers (A-layout: m=lane&15, k=quad*8+j), scale folded in prep
  short8 qh[2][2], ql[2][2];
#pragma unroll
  for (int t = 0; t < 2; t++) {
    const int l = lB + wave * 32 + t * 16 + l16;
    const size_t base = (size_t)(b * cL + l) * cD + h * cHD + quad * 8;
#pragma unroll
    for (int ks = 0; ks < 2; ks++) {
      qh[t][ks] = *(const short8*)(qhi + base + ks * 32);
      ql[t][ks] = *(const short8*)(qlo + base + ks * 32);
    }
  }

  f32x4 O[2][4];
  float mrow[2][4], den[2][4];
#pragma unroll
  for (int t = 0; t < 2; t++)
#pragma unroll
    for (int i = 0; i < 4; i++) {
      O[t][i] = (f32x4){0.f, 0.f, 0.f, 0.f};
      mrow[t][i] = -INFINITY;
      den[t][i] = 0.f;
    }

  // staging assignments: K: 32 rows x 8 granules; V: 64 rows x 4 granules (1 each/thread)
  const int krow = tid >> 3, kg = (tid & 7) * 8;
  const int vrow = tid >> 2, vg = (tid & 3) * 8;
  const size_t kgbase = (size_t)(b * cS) * cD + h * cHD;
  const size_t vgbase = (size_t)(b * cD + h * cHD + vrow) * cS;

  for (int s0 = 0; s0 < cS; s0 += 32) {
    const size_t ka = kgbase + (size_t)(s0 + krow) * cD + kg;
    const uint4 rkh = *(const uint4*)(Khi + ka);
    const uint4 rkl = *(const uint4*)(Klo + ka);
    const size_t va = vgbase + s0 + vg;
    const uint4 rvh = *(const uint4*)(Vthi + va);
    const uint4 rvl = *(const uint4*)(Vtlo + va);
    __syncthreads();
    *(uint4*)&sKhi[krow][kg] = rkh;
    *(uint4*)&sKlo[krow][kg] = rkl;
    *(uint4*)&sVhi[vrow][vg] = rvh;
    *(uint4*)&sVlo[vrow][vg] = rvl;
    __syncthreads();

    // QK^T with 3-term split (q,k hi/lo)
    f32x4 sc[2][2];
#pragma unroll
    for (int t = 0; t < 2; t++)
#pragma unroll
      for (int st = 0; st < 2; st++) sc[t][st] = (f32x4){0.f, 0.f, 0.f, 0.f};
#pragma unroll
    for (int ks = 0; ks < 2; ks++) {
#pragma unroll
      for (int st = 0; st < 2; st++) {
        const short8 kfh = *(const short8*)&sKhi[st * 16 + l16][ks * 32 + quad * 8];
        const short8 kfl = *(const short8*)&sKlo[st * 16 + l16][ks * 32 + quad * 8];
#pragma unroll
        for (int t = 0; t < 2; t++) {
          sc[t][st] = MFMA16(qh[t][ks], kfh, sc[t][st]);
          sc[t][st] = MFMA16(ql[t][ks], kfh, sc[t][st]);
          sc[t][st] = MFMA16(qh[t][ks], kfl, sc[t][st]);
        }
      }
    }

    // online softmax (rows owned in C-layout: row = quad*4+r, col s = st*16+l16)
#pragma unroll
    for (int t = 0; t < 2; t++) {
      float mx[4], rs[4], al[4];
#pragma unroll
      for (int r = 0; r < 4; r++) mx[r] = fmaxf(sc[t][0][r], sc[t][1][r]);
#pragma unroll
      for (int o = 1; o < 16; o <<= 1)
#pragma unroll
        for (int r = 0; r < 4; r++) mx[r] = fmaxf(mx[r], __shfl_xor(mx[r], o, 64));
#pragma unroll
      for (int r = 0; r < 4; r++) {
        const float mn = fmaxf(mrow[t][r], mx[r]);
        al[r] = __expf(mrow[t][r] - mn);
        mrow[t][r] = mn;
        const float p0 = __expf(sc[t][0][r] - mn);
        const float p1 = __expf(sc[t][1][r] - mn);
        sc[t][0][r] = p0;
        sc[t][1][r] = p1;
        rs[r] = p0 + p1;
      }
#pragma unroll
      for (int o = 1; o < 16; o <<= 1)
#pragma unroll
        for (int r = 0; r < 4; r++) rs[r] += __shfl_xor(rs[r], o, 64);
#pragma unroll
      for (int r = 0; r < 4; r++) den[t][r] = den[t][r] * al[r] + rs[r];
#pragma unroll
      for (int dt = 0; dt < 4; dt++)
#pragma unroll
        for (int r = 0; r < 4; r++) O[t][dt][r] *= al[r];
      // write P (hi/lo bf16) to per-wave LDS
#pragma unroll
      for (int st = 0; st < 2; st++)
#pragma unroll
        for (int r = 0; r < 4; r++) {
          const float p = sc[t][st][r];
          const unsigned short ph = f2bf(p);
          sP[wave][t][0][quad * 4 + r][st * 16 + l16] = ph;
          sP[wave][t][1][quad * 4 + r][st * 16 + l16] = f2bf(p - bf2f(ph));
        }
    }

    // P fragments (A-layout) — wave-local, compiler inserts lgkmcnt wait
    short8 pf[2][2];
#pragma unroll
    for (int t = 0; t < 2; t++) {
      pf[t][0] = *(const short8*)&sP[wave][t][0][l16][quad * 8];
      pf[t][1] = *(const short8*)&sP[wave][t][1][l16][quad * 8];
    }
    // PV with 3-term split (p,v hi/lo)
#pragma unroll
    for (int dt = 0; dt < 4; dt++) {
      const short8 vfh = *(const short8*)&sVhi[dt * 16 + l16][quad * 8];
      const short8 vfl = *(const short8*)&sVlo[dt * 16 + l16][quad * 8];
#pragma unroll
      for (int t = 0; t < 2; t++) {
        O[t][dt] = MFMA16(pf[t][0], vfh, O[t][dt]);
        O[t][dt] = MFMA16(pf[t][0], vfl, O[t][dt]);
        O[t][dt] = MFMA16(pf[t][1], vfh, O[t][dt]);
      }
    }
  }

  // epilogue: rows quad*4+r, cols dt*16+l16
#pragma unroll
  for (int t = 0; t < 2; t++) {
    float inv[4];
#pragma unroll
    for (int r = 0; r < 4; r++) inv[r] = 1.f / den[t][r];
#pragma unroll
    for (int dt = 0; dt < 4; dt++)
#pragma unroll
      for (int r = 0; r < 4; r++) {
        const size_t l = (size_t)(b * cL + lB + wave * 32 + t * 16 + quad * 4 + r);
        AO[l * cD + h * cHD + dt * 16 + l16] = O[t][dt][r] * inv[r];
      }
  }
}

}  // namespace

extern "C" void kernel_launch(void* const* d_in, const int* in_sizes, int n_in,
                              void* d_out, int out_size, void* d_ws, size_t ws_size,
                              hipStream_t stream) {
  (void)in_sizes; (void)n_in; (void)out_size; (void)ws_size;
  const float* x_q = (const float*)d_in[0];
  const int* x_idx = (const int*)d_in[1];
  const float* E_slots = (const float*)d_in[2];
  const float* rhos = (const float*)d_in[3];
  const float* C_seq = (const float*)d_in[4];
  const float* Wq = (const float*)d_in[5];
  const float* Wk = (const float*)d_in[6];
  const float* Wv = (const float*)d_in[7];
  const float* Wo = (const float*)d_in[8];
  const float* Wpe = (const float*)d_in[9];
  const float* ln_kv_g = (const float*)d_in[10];
  const float* ln_kv_b = (const float*)d_in[11];
  const float* ln_q_g = (const float*)d_in[12];
  const float* ln_q_b = (const float*)d_in[13];
  float* out = (float*)d_out;

  float* ws = (float*)d_ws;
  // fp32 regions (floats)
  float* mem = ws + 0;            // 524288
  float* Ek = ws + 524288;        // 524288
  float* Ev = ws + 1048576;       // 524288
  float* gkv = ws + 1572864;      // 2097152
  float* Y = ws + 3670016;        // 4194304
  float* Qb = ws + 7864320;       // 4194304
  // bf16 regions (each B*S*D = 4194304 ushorts = 2097152 float-slots)
  unsigned short* Khi = (unsigned short*)(ws + 12058624);
  unsigned short* Klo = (unsigned short*)(ws + 14155776);
  unsigned short* Vthi = (unsigned short*)(ws + 16252928);
  unsigned short* Vtlo = (unsigned short*)(ws + 18350080);
  // aliased (lifetimes disjoint):
  unsigned short* qhi = (unsigned short*)(ws + 0);        // over mem/Ek/Ev/gkv-head (free by prep_q)
  unsigned short* qlo = (unsigned short*)(ws + 3670016);  // over Y (free after Q GEMM)
  float* AO = ws + 7864320;                               // over Qb (free after prep_q)
  // total ws extent: 20447232 floats ~= 82 MB

  ln_slots_kernel<<<cNSLOT, 256, 0, stream>>>(E_slots, ln_kv_g, ln_kv_b, mem);
  gemm_nt_kernel<<<dim3(cD / 128, cNSLOT / 128), 256, 0, stream>>>(mem, Wk, Ek, cNSLOT, cD, cD);
  gemm_nt_kernel<<<dim3(cD / 128, cNSLOT / 128), 256, 0, stream>>>(mem, Wv, Ev, cNSLOT, cD, cD);
  gatekv_kernel<<<cS, 256, 0, stream>>>(rhos, Wpe, gkv);
  prep_k_kernel<<<2048, 256, 0, stream>>>(Ek, gkv, x_idx, Khi, Klo);
  prep_vt_kernel<<<dim3(cS / 64, cD / 64, cB), 256, 0, stream>>>(Ev, gkv, x_idx, Vthi, Vtlo);
  qgate_ln_kernel<<<cB * cL, 256, 0, stream>>>(x_q, C_seq, Wpe, ln_q_g, ln_q_b, Y);
  gemm_nt_kernel<<<dim3(cD / 128, (cB * cL) / 128), 256, 0, stream>>>(Y, Wq, Qb, cB * cL, cD, cD);
  prep_q_kernel<<<2048, 256, 0, stream>>>(Qb, qhi, qlo);
  attn_mfma_kernel<<<dim3(cL / 128, cH, cB), 256, 0, stream>>>(qhi, qlo, Khi, Klo, Vthi, Vtlo, AO);
  gemm_nt_kernel<<<dim3(cD / 128, (cB * cL) / 128), 256, 0, stream>>>(AO, Wo, out, cB * cL, cD, cD);
}

// Round 3
// 475.214 us; speedup vs baseline: 3.4586x; 1.8163x over previous
//
#include <hip/hip_runtime.h>
#include <cmath>
#include <cstddef>

namespace {

constexpr int cB = 2, cL = 2048, cS = 2048, cD = 1024, cH = 16, cNS = 8, cNSLOT = 512, cHD = 64;

typedef __attribute__((ext_vector_type(8))) short short8;
typedef __attribute__((ext_vector_type(4))) float f32x4;

#define MFMA16(a, b, c) __builtin_amdgcn_mfma_f32_16x16x32_bf16((a), (b), (c), 0, 0, 0)

__device__ __forceinline__ float sigmoidf_(float x) { return 1.f / (1.f + __expf(-x)); }

__device__ __forceinline__ unsigned short f2bf(float x) {
  union { float f; unsigned u; } c; c.f = x;
  unsigned r = c.u + 0x7FFFu + ((c.u >> 16) & 1u);
  return (unsigned short)(r >> 16);
}
__device__ __forceinline__ float bf2f(unsigned short h) {
  union { unsigned u; float f; } c; c.u = ((unsigned)h) << 16;
  return c.f;
}

// async global->LDS 16B per lane. lds ptr must be wave-uniform base; HW writes base + lane*16.
__device__ __forceinline__ void async16(const void* g, void* l) {
  __builtin_amdgcn_global_load_lds((const __attribute__((address_space(1))) void*)g,
                                   (__attribute__((address_space(3))) void*)l, 16, 0, 0);
}

// ---------------- weight split: 4 matrices of 1M floats -> hi/lo bf16 ----------------
__global__ __launch_bounds__(256) void wsplit_kernel(
    const float* __restrict__ Wq, const float* __restrict__ Wk,
    const float* __restrict__ Wv, const float* __restrict__ Wo,
    unsigned short* __restrict__ Wqh, unsigned short* __restrict__ Wql,
    unsigned short* __restrict__ Wkh, unsigned short* __restrict__ Wkl,
    unsigned short* __restrict__ Wvh, unsigned short* __restrict__ Wvl,
    unsigned short* __restrict__ Woh, unsigned short* __restrict__ Wol) {
  const int wid = blockIdx.x >> 9;  // 512 blocks per weight
  const size_t off = ((size_t)(blockIdx.x & 511) * 256 + threadIdx.x) * 8;
  const float* src = wid == 0 ? Wq : wid == 1 ? Wk : wid == 2 ? Wv : Wo;
  unsigned short* dh = wid == 0 ? Wqh : wid == 1 ? Wkh : wid == 2 ? Wvh : Woh;
  unsigned short* dl = wid == 0 ? Wql : wid == 1 ? Wkl : wid == 2 ? Wvl : Wol;
  const float4 a = *(const float4*)(src + off);
  const float4 b = *(const float4*)(src + off + 4);
  float v[8] = {a.x, a.y, a.z, a.w, b.x, b.y, b.z, b.w};
  unsigned short h8[8], l8[8];
#pragma unroll
  for (int j = 0; j < 8; j++) {
    h8[j] = f2bf(v[j]);
    l8[j] = f2bf(v[j] - bf2f(h8[j]));
  }
  *(uint4*)(dh + off) = *(uint4*)h8;
  *(uint4*)(dl + off) = *(uint4*)l8;
}

// ---------------- LayerNorm of E_slots rows -> hi/lo bf16 ----------------
__global__ __launch_bounds__(256) void ln_slots_kernel(const float* __restrict__ E,
                                                       const float* __restrict__ gamma,
                                                       const float* __restrict__ beta,
                                                       unsigned short* __restrict__ mh,
                                                       unsigned short* __restrict__ ml) {
  __shared__ float rbuf[8];
  const int row = blockIdx.x;
  const int tid = threadIdx.x;
  const int d0 = tid * 4;
  const float4 x = *(const float4*)(E + (size_t)row * cD + d0);
  float s1 = x.x + x.y + x.z + x.w;
  float s2 = x.x * x.x + x.y * x.y + x.z * x.z + x.w * x.w;
#pragma unroll
  for (int o = 32; o > 0; o >>= 1) { s1 += __shfl_xor(s1, o, 64); s2 += __shfl_xor(s2, o, 64); }
  if ((tid & 63) == 0) { rbuf[tid >> 6] = s1; rbuf[4 + (tid >> 6)] = s2; }
  __syncthreads();
  s1 = rbuf[0] + rbuf[1] + rbuf[2] + rbuf[3];
  s2 = rbuf[4] + rbuf[5] + rbuf[6] + rbuf[7];
  const float mean = s1 * (1.f / cD);
  const float var = s2 * (1.f / cD) - mean * mean;
  const float inv = rsqrtf(var + 1e-5f);
  const float4 g = *(const float4*)(gamma + d0);
  const float4 b = *(const float4*)(beta + d0);
  float y[4];
  y[0] = (x.x - mean) * inv * g.x + b.x;
  y[1] = (x.y - mean) * inv * g.y + b.y;
  y[2] = (x.z - mean) * inv * g.z + b.z;
  y[3] = (x.w - mean) * inv * g.w + b.w;
  unsigned short h4[4], l4[4];
#pragma unroll
  for (int j = 0; j < 4; j++) {
    h4[j] = f2bf(y[j]);
    l4[j] = f2bf(y[j] - bf2f(h4[j]));
  }
  *(uint2*)(mh + (size_t)row * cD + d0) = *(uint2*)h4;
  *(uint2*)(ml + (size_t)row * cD + d0) = *(uint2*)l4;
}

// ---------------- Q-side: Y = LN(x_q * SiLU(C_seq @ Wpe^T)) -> hi/lo bf16 ----------------
__global__ __launch_bounds__(256) void qgate_ln_kernel(const float* __restrict__ xq,
                                                       const float* __restrict__ Cseq,
                                                       const float* __restrict__ Wpe,
                                                       const float* __restrict__ gamma,
                                                       const float* __restrict__ beta,
                                                       unsigned short* __restrict__ Yh,
                                                       unsigned short* __restrict__ Yl) {
  __shared__ float sC[cNS];
  __shared__ float rbuf[8];
  const int row = blockIdx.x;
  const int tid = threadIdx.x;
  if (tid < cNS) sC[tid] = Cseq[(size_t)row * cNS + tid];
  __syncthreads();
  const int d0 = tid * 4;
  const float4 x = *(const float4*)(xq + (size_t)row * cD + d0);
  float y[4];
  float s1 = 0.f, s2 = 0.f;
#pragma unroll
  for (int j = 0; j < 4; j++) {
    const float* wr = Wpe + (size_t)(d0 + j) * cNS;
    float gs = 0.f;
#pragma unroll
    for (int m = 0; m < cNS; m++) gs += sC[m] * wr[m];
    const float val = ((const float*)&x)[j] * gs * sigmoidf_(gs);
    y[j] = val;
    s1 += val;
    s2 += val * val;
  }
#pragma unroll
  for (int o = 32; o > 0; o >>= 1) { s1 += __shfl_xor(s1, o, 64); s2 += __shfl_xor(s2, o, 64); }
  if ((tid & 63) == 0) { rbuf[tid >> 6] = s1; rbuf[4 + (tid >> 6)] = s2; }
  __syncthreads();
  s1 = rbuf[0] + rbuf[1] + rbuf[2] + rbuf[3];
  s2 = rbuf[4] + rbuf[5] + rbuf[6] + rbuf[7];
  const float mean = s1 * (1.f / cD);
  const float var = s2 * (1.f / cD) - mean * mean;
  const float inv = rsqrtf(var + 1e-5f);
  const float4 g = *(const float4*)(gamma + d0);
  const float4 b = *(const float4*)(beta + d0);
  float z[4];
  z[0] = (y[0] - mean) * inv * g.x + b.x;
  z[1] = (y[1] - mean) * inv * g.y + b.y;
  z[2] = (y[2] - mean) * inv * g.z + b.z;
  z[3] = (y[3] - mean) * inv * g.w + b.w;
  unsigned short h4[4], l4[4];
#pragma unroll
  for (int j = 0; j < 4; j++) {
    h4[j] = f2bf(z[j]);
    l4[j] = f2bf(z[j] - bf2f(h4[j]));
  }
  *(uint2*)(Yh + (size_t)row * cD + d0) = *(uint2*)h4;
  *(uint2*)(Yl + (size_t)row * cD + d0) = *(uint2*)l4;
}

// ---------------- gate_kv[s, d] = SiLU( sum_m rho_m^(S-1-s) * Wpe[d, m] ) ----------------
__global__ __launch_bounds__(256) void gatekv_kernel(const float* __restrict__ rhos,
                                                     const float* __restrict__ Wpe,
                                                     float* __restrict__ gkv) {
  __shared__ float sC[cNS];
  const int s = blockIdx.x;
  const int tid = threadIdx.x;
  if (tid < cNS) {
    const float age = (float)(cS - 1 - s);
    sC[tid] = __expf(age * __logf(rhos[tid]));
  }
  __syncthreads();
  const int d0 = tid * 4;
  float4 o4;
#pragma unroll
  for (int j = 0; j < 4; j++) {
    const float* wr = Wpe + (size_t)(d0 + j) * cNS;
    float gs = 0.f;
#pragma unroll
    for (int m = 0; m < cNS; m++) gs += sC[m] * wr[m];
    ((float*)&o4)[j] = gs * sigmoidf_(gs);
  }
  *(float4*)(gkv + (size_t)s * cD + d0) = o4;
}

// ---------------- split-bf16 MFMA GEMM: C[M,N] = A[M,K] @ W[N,K]^T ----------------
// 128x128 tile, BK=32, 256 thr (4 waves, 2x2), double-buffered LDS w/ prefetch-after-barrier.
// LDS granule slot g holds global granule g ^ ((row>>1)&3) so frag ds_read_b128 is 2-way only.
// MODE 0: fp32 out. MODE 1: scale then hi/lo bf16 split out.
template <int MODE>
__global__ __launch_bounds__(256) void gemm_sp_kernel(
    const unsigned short* __restrict__ Ahi, const unsigned short* __restrict__ Alo,
    const unsigned short* __restrict__ Whi, const unsigned short* __restrict__ Wlo,
    float* __restrict__ Cf, unsigned short* __restrict__ Chi, unsigned short* __restrict__ Clo,
    int M, int N, int K, float scale) {
  __shared__ __align__(16) unsigned short sAh[2][128 * 32];
  __shared__ __align__(16) unsigned short sAl[2][128 * 32];
  __shared__ __align__(16) unsigned short sBh[2][128 * 32];
  __shared__ __align__(16) unsigned short sBl[2][128 * 32];
  const int tid = threadIdx.x;
  const int wave = tid >> 6, lane = tid & 63;
  const int quad = lane >> 4, l16 = lane & 15;
  const int m0 = blockIdx.y * 128, n0 = blockIdx.x * 128;
  const int wy = wave >> 1, wx = wave & 1;
  const int srow = lane >> 2;                     // row within 16-row staging inst
  const int sg = (lane & 3) ^ ((lane >> 3) & 3);  // permuted global granule

  f32x4 acc[4][4];
#pragma unroll
  for (int i = 0; i < 4; i++)
#pragma unroll
    for (int j = 0; j < 4; j++) acc[i][j] = (f32x4){0.f, 0.f, 0.f, 0.f};

  // stage one BK=32 slab of A,B (hi+lo) into buffer `buf`
  auto stage = [&](int buf, int k0) {
#pragma unroll
    for (int c = 0; c < 2; c++) {
      const int j = wave * 2 + c;  // staging inst 0..7, rows j*16..j*16+15
      const int row = j * 16 + srow;
      const size_t ga = (size_t)(m0 + row) * K + k0 + sg * 8;
      const size_t gb = (size_t)(n0 + row) * K + k0 + sg * 8;
      async16(Ahi + ga, &sAh[buf][j * 512]);
      async16(Alo + ga, &sAl[buf][j * 512]);
      async16(Whi + gb, &sBh[buf][j * 512]);
      async16(Wlo + gb, &sBl[buf][j * 512]);
    }
  };

  stage(0, 0);
  __syncthreads();
  const int aswz = (l16 >> 1) & 3;
  int buf = 0;
  for (int k0 = 0; k0 < K; k0 += 32, buf ^= 1) {
    if (k0 + 32 < K) stage(buf ^ 1, k0 + 32);  // prefetch AFTER barrier: drains at iter-end barrier
    short8 bh[4], bl4[4];
#pragma unroll
    for (int t = 0; t < 4; t++) {
      const int br = (wx * 64 + t * 16 + l16) * 32 + ((quad ^ aswz) * 8);
      bh[t] = *(const short8*)&sBh[buf][br];
      bl4[t] = *(const short8*)&sBl[buf][br];
    }
#pragma unroll
    for (int ti = 0; ti < 4; ti++) {
      const int ar = (wy * 64 + ti * 16 + l16) * 32 + ((quad ^ aswz) * 8);
      const short8 ah = *(const short8*)&sAh[buf][ar];
      const short8 al4 = *(const short8*)&sAl[buf][ar];
#pragma unroll
      for (int tj = 0; tj < 4; tj++) {
        acc[ti][tj] = MFMA16(ah, bh[tj], acc[ti][tj]);
        acc[ti][tj] = MFMA16(al4, bh[tj], acc[ti][tj]);
        acc[ti][tj] = MFMA16(ah, bl4[tj], acc[ti][tj]);
      }
    }
    __syncthreads();
  }

#pragma unroll
  for (int ti = 0; ti < 4; ti++)
#pragma unroll
    for (int tj = 0; tj < 4; tj++) {
      const int row = m0 + wy * 64 + ti * 16 + quad * 4;
      const int col = n0 + wx * 64 + tj * 16 + l16;
#pragma unroll
      for (int r = 0; r < 4; r++) {
        const size_t idx = (size_t)(row + r) * N + col;
        if constexpr (MODE == 0) {
          Cf[idx] = acc[ti][tj][r];
        } else {
          const float v = acc[ti][tj][r] * scale;
          const unsigned short hi = f2bf(v);
          Chi[idx] = hi;
          Clo[idx] = f2bf(v - bf2f(hi));
        }
      }
    }
}

// ---------------- prep: K = gather(Ek)*gate, split hi/lo bf16, [B][S][D] ----------------
__global__ __launch_bounds__(256) void prep_k_kernel(const float* __restrict__ Ek,
                                                     const float* __restrict__ gkv,
                                                     const int* __restrict__ xidx,
                                                     unsigned short* __restrict__ Khi,
                                                     unsigned short* __restrict__ Klo) {
  const int t = blockIdx.x * 256 + threadIdx.x;
  const int d0 = (t & 127) * 8;
  const int s = (t >> 7) & (cS - 1);
  const int b = t >> 18;
  const int slot = xidx[b * cS + s];
  const float4 e0 = *(const float4*)(Ek + (size_t)slot * cD + d0);
  const float4 e1 = *(const float4*)(Ek + (size_t)slot * cD + d0 + 4);
  const float4 g0 = *(const float4*)(gkv + (size_t)s * cD + d0);
  const float4 g1 = *(const float4*)(gkv + (size_t)s * cD + d0 + 4);
  float v[8] = {e0.x * g0.x, e0.y * g0.y, e0.z * g0.z, e0.w * g0.w,
                e1.x * g1.x, e1.y * g1.y, e1.z * g1.z, e1.w * g1.w};
  unsigned short h8[8], l8[8];
#pragma unroll
  for (int j = 0; j < 8; j++) {
    h8[j] = f2bf(v[j]);
    l8[j] = f2bf(v[j] - bf2f(h8[j]));
  }
  const size_t off = (size_t)(b * cS + s) * cD + d0;
  *(uint4*)(Khi + off) = *(uint4*)h8;
  *(uint4*)(Klo + off) = *(uint4*)l8;
}

// ---------------- prep: Vt[b][d][s] = gather(Ev)*gate, split hi/lo bf16 (transposed) ----------------
__global__ __launch_bounds__(256) void prep_vt_kernel(const float* __restrict__ Ev,
                                                      const float* __restrict__ gkv,
                                                      const int* __restrict__ xidx,
                                                      unsigned short* __restrict__ Vthi,
                                                      unsigned short* __restrict__ Vtlo) {
  __shared__ float tile[64][65];
  const int s0 = blockIdx.x * 64, d0 = blockIdx.y * 64, b = blockIdx.z;
  const int tid = threadIdx.x;
  const int sl = tid >> 4;
  const int dl = (tid & 15) * 4;
#pragma unroll
  for (int it = 0; it < 4; it++) {
    const int s = s0 + sl + it * 16;
    const int slot = xidx[b * cS + s];
    const float4 e = *(const float4*)(Ev + (size_t)slot * cD + d0 + dl);
    const float4 g = *(const float4*)(gkv + (size_t)s * cD + d0 + dl);
    tile[sl + it * 16][dl + 0] = e.x * g.x;
    tile[sl + it * 16][dl + 1] = e.y * g.y;
    tile[sl + it * 16][dl + 2] = e.z * g.z;
    tile[sl + it * 16][dl + 3] = e.w * g.w;
  }
  __syncthreads();
  const int dr = tid >> 3;
  const int sc = (tid & 7) * 8;
#pragma unroll
  for (int it = 0; it < 2; it++) {
    const int d = d0 + dr + it * 32;
    unsigned short h8[8], l8[8];
#pragma unroll
    for (int j = 0; j < 8; j++) {
      const float v = tile[sc + j][dr + it * 32];
      h8[j] = f2bf(v);
      l8[j] = f2bf(v - bf2f(h8[j]));
    }
    const size_t off = (size_t)(b * cD + d) * cS + s0 + sc;
    *(uint4*)(Vthi + off) = *(uint4*)h8;
    *(uint4*)(Vtlo + off) = *(uint4*)l8;
  }
}

// ---------------- MFMA flash attention v2 ----------------
// grid (L/64, H, B) = 1024 blocks, 256 thr = 4 waves, wave owns 16 l-rows. s-chunk 64.
// K/V staged via global_load_lds with XOR granule permute (conflict-free frag reads).
__global__ __launch_bounds__(256, 3) void attn_mfma_kernel(
    const unsigned short* __restrict__ qhi, const unsigned short* __restrict__ qlo,
    const unsigned short* __restrict__ Khi, const unsigned short* __restrict__ Klo,
    const unsigned short* __restrict__ Vthi, const unsigned short* __restrict__ Vtlo,
    unsigned short* __restrict__ AOhi, unsigned short* __restrict__ AOlo) {
  __shared__ __align__(16) unsigned short sKh[64 * 64];
  __shared__ __align__(16) unsigned short sKl[64 * 64];
  __shared__ __align__(16) unsigned short sVh[64 * 64];
  __shared__ __align__(16) unsigned short sVl[64 * 64];
  __shared__ __align__(16) unsigned short sP[4][2][16][72];

  const int tid = threadIdx.x;
  const int wave = tid >> 6, lane = tid & 63;
  const int quad = lane >> 4, l16 = lane & 15;
  const int lB = blockIdx.x * 64;
  const int h = blockIdx.y, b = blockIdx.z;

  // Q fragments (A-layout), 1/8 scale folded upstream
  short8 qh[2], ql[2];
  {
    const size_t base = (size_t)(b * cL + lB + wave * 16 + l16) * cD + h * cHD + quad * 8;
    qh[0] = *(const short8*)(qhi + base);
    qh[1] = *(const short8*)(qhi + base + 32);
    ql[0] = *(const short8*)(qlo + base);
    ql[1] = *(const short8*)(qlo + base + 32);
  }

  f32x4 O[4];
  float mrow[4], den[4];
#pragma unroll
  for (int i = 0; i < 4; i++) {
    O[i] = (f32x4){0.f, 0.f, 0.f, 0.f};
    mrow[i] = -INFINITY;
    den[i] = 0.f;
  }

  const int srow8 = lane >> 3;           // row within 8-row staging inst
  const int sg = (lane & 7) ^ srow8;     // permuted global granule

  for (int s0 = 0; s0 < cS; s0 += 64) {
    __syncthreads();  // all waves done reading sK/sV from prior iter
#pragma unroll
    for (int c = 0; c < 2; c++) {
      const int j = wave * 2 + c;  // inst 0..7, rows j*8..j*8+7
      const int r = j * 8 + srow8;
      const size_t ka = (size_t)(b * cS + s0 + r) * cD + h * cHD + sg * 8;
      async16(Khi + ka, &sKh[j * 512]);
      async16(Klo + ka, &sKl[j * 512]);
      const size_t va = (size_t)(b * cD + h * cHD + r) * cS + s0 + sg * 8;
      async16(Vthi + va, &sVh[j * 512]);
      async16(Vtlo + va, &sVl[j * 512]);
    }
    __syncthreads();  // vmcnt(0) drain: staged data visible

    // QK^T, 3-term split
    f32x4 sc[4];
#pragma unroll
    for (int st = 0; st < 4; st++) sc[st] = (f32x4){0.f, 0.f, 0.f, 0.f};
#pragma unroll
    for (int st = 0; st < 4; st++) {
      const int srw = st * 16 + l16;
#pragma unroll
      for (int ks = 0; ks < 2; ks++) {
        const int slot = (ks * 4 + quad) ^ (srw & 7);
        const short8 kfh = *(const short8*)&sKh[srw * 64 + slot * 8];
        const short8 kfl = *(const short8*)&sKl[srw * 64 + slot * 8];
        sc[st] = MFMA16(qh[ks], kfh, sc[st]);
        sc[st] = MFMA16(ql[ks], kfh, sc[st]);
        sc[st] = MFMA16(qh[ks], kfl, sc[st]);
      }
    }

    // online softmax over 64 cols (C-layout: row=quad*4+r, col=st*16+l16)
    float mx[4], al[4], rs[4], mn[4];
#pragma unroll
    for (int r = 0; r < 4; r++)
      mx[r] = fmaxf(fmaxf(sc[0][r], sc[1][r]), fmaxf(sc[2][r], sc[3][r]));
#pragma unroll
    for (int o = 1; o < 16; o <<= 1)
#pragma unroll
      for (int r = 0; r < 4; r++) mx[r] = fmaxf(mx[r], __shfl_xor(mx[r], o, 64));
#pragma unroll
    for (int r = 0; r < 4; r++) {
      mn[r] = fmaxf(mrow[r], mx[r]);
      al[r] = __expf(mrow[r] - mn[r]);
      mrow[r] = mn[r];
      rs[r] = 0.f;
    }
#pragma unroll
    for (int st = 0; st < 4; st++)
#pragma unroll
      for (int r = 0; r < 4; r++) {
        const float p = __expf(sc[st][r] - mn[r]);
        sc[st][r] = p;
        rs[r] += p;
      }
#pragma unroll
    for (int o = 1; o < 16; o <<= 1)
#pragma unroll
      for (int r = 0; r < 4; r++) rs[r] += __shfl_xor(rs[r], o, 64);
#pragma unroll
    for (int r = 0; r < 4; r++) den[r] = den[r] * al[r] + rs[r];
#pragma unroll
    for (int dt = 0; dt < 4; dt++)
#pragma unroll
      for (int r = 0; r < 4; r++) O[dt][r] *= al[r];
    // P -> per-wave LDS (hi/lo)
#pragma unroll
    for (int st = 0; st < 4; st++)
#pragma unroll
      for (int r = 0; r < 4; r++) {
        const float p = sc[st][r];
        const unsigned short ph = f2bf(p);
        sP[wave][0][quad * 4 + r][st * 16 + l16] = ph;
        sP[wave][1][quad * 4 + r][st * 16 + l16] = f2bf(p - bf2f(ph));
      }

    // P fragments (A-layout), wave-local
    short8 pfh[2], pfl[2];
#pragma unroll
    for (int ss = 0; ss < 2; ss++) {
      pfh[ss] = *(const short8*)&sP[wave][0][l16][ss * 32 + quad * 8];
      pfl[ss] = *(const short8*)&sP[wave][1][l16][ss * 32 + quad * 8];
    }
    // PV, 3-term split
#pragma unroll
    for (int dt = 0; dt < 4; dt++) {
      const int drw = dt * 16 + l16;
#pragma unroll
      for (int ss = 0; ss < 2; ss++) {
        const int slot = (ss * 4 + quad) ^ (drw & 7);
        const short8 vfh = *(const short8*)&sVh[drw * 64 + slot * 8];
        const short8 vfl = *(const short8*)&sVl[drw * 64 + slot * 8];
        O[dt] = MFMA16(pfh[ss], vfh, O[dt]);
        O[dt] = MFMA16(pfh[ss], vfl, O[dt]);
        O[dt] = MFMA16(pfl[ss], vfh, O[dt]);
      }
    }
  }

  // epilogue: split to AOhi/AOlo. row = quad*4+r, col = dt*16+l16
  float inv[4];
#pragma unroll
  for (int r = 0; r < 4; r++) inv[r] = 1.f / den[r];
#pragma unroll
  for (int dt = 0; dt < 4; dt++)
#pragma unroll
    for (int r = 0; r < 4; r++) {
      const float v = O[dt][r] * inv[r];
      const unsigned short hi = f2bf(v);
      const size_t l = (size_t)(b * cL + lB + wave * 16 + quad * 4 + r);
      const size_t idx = l * cD + h * cHD + dt * 16 + l16;
      AOhi[idx] = hi;
      AOlo[idx] = f2bf(v - bf2f(hi));
    }
}

}  // namespace

extern "C" void kernel_launch(void* const* d_in, const int* in_sizes, int n_in,
                              void* d_out, int out_size, void* d_ws, size_t ws_size,
                              hipStream_t stream) {
  (void)in_sizes; (void)n_in; (void)out_size; (void)ws_size;
  const float* x_q = (const float*)d_in[0];
  const int* x_idx = (const int*)d_in[1];
  const float* E_slots = (const float*)d_in[2];
  const float* rhos = (const float*)d_in[3];
  const float* C_seq = (const float*)d_in[4];
  const float* Wq = (const float*)d_in[5];
  const float* Wk = (const float*)d_in[6];
  const float* Wv = (const float*)d_in[7];
  const float* Wo = (const float*)d_in[8];
  const float* Wpe = (const float*)d_in[9];
  const float* ln_kv_g = (const float*)d_in[10];
  const float* ln_kv_b = (const float*)d_in[11];
  const float* ln_q_g = (const float*)d_in[12];
  const float* ln_q_b = (const float*)d_in[13];
  float* out = (float*)d_out;

  float* ws = (float*)d_ws;
  // offsets in float units (ushort arrays use 2 entries per float slot)
  unsigned short* memhi = (unsigned short*)(ws + 0);        // 512K ushort (NSLOT*D)
  unsigned short* memlo = (unsigned short*)(ws + 262144);
  unsigned short* Wkhi = (unsigned short*)(ws + 524288);    // 1M ushort each
  unsigned short* Wklo = (unsigned short*)(ws + 1048576);
  unsigned short* Wvhi = (unsigned short*)(ws + 1572864);
  unsigned short* Wvlo = (unsigned short*)(ws + 2097152);
  float* gkv = ws + 2621440;                                // 2M floats [S,D]
  // qhi/qlo overlay mem+WkWv+gkv region (all dead before Q GEMM writes them)
  unsigned short* qhi = (unsigned short*)(ws + 0);          // 4M ushort (B*L*D)
  unsigned short* qlo = (unsigned short*)(ws + 2097152);
  unsigned short* Wqhi = (unsigned short*)(ws + 4718592);
  unsigned short* Wqlo = (unsigned short*)(ws + 5242880);
  unsigned short* Wohi = (unsigned short*)(ws + 5767168);
  unsigned short* Wolo = (unsigned short*)(ws + 6291456);
  float* Ek = ws + 6815744;                                 // 512K floats
  float* Ev = ws + 7340032;
  unsigned short* Yhi = (unsigned short*)(ws + 7864320);    // 4M ushort
  unsigned short* Ylo = (unsigned short*)(ws + 9961472);
  unsigned short* AOhi = (unsigned short*)(ws + 7864320);   // overlay Y (dead after Q GEMM)
  unsigned short* AOlo = (unsigned short*)(ws + 9961472);
  unsigned short* Khi = (unsigned short*)(ws + 12058624);
  unsigned short* Klo = (unsigned short*)(ws + 14155776);
  unsigned short* Vthi = (unsigned short*)(ws + 16252928);
  unsigned short* Vtlo = (unsigned short*)(ws + 18350080);
  // extent: 20447232 floats ~= 82 MB

  wsplit_kernel<<<2048, 256, 0, stream>>>(Wq, Wk, Wv, Wo, Wqhi, Wqlo, Wkhi, Wklo,
                                          Wvhi, Wvlo, Wohi, Wolo);
  ln_slots_kernel<<<cNSLOT, 256, 0, stream>>>(E_slots, ln_kv_g, ln_kv_b, memhi, memlo);
  gemm_sp_kernel<0><<<dim3(8, 4), 256, 0, stream>>>(memhi, memlo, Wkhi, Wklo, Ek, nullptr,
                                                    nullptr, cNSLOT, cD, cD, 1.f);
  gemm_sp_kernel<0><<<dim3(8, 4), 256, 0, stream>>>(memhi, memlo, Wvhi, Wvlo, Ev, nullptr,
                                                    nullptr, cNSLOT, cD, cD, 1.f);
  gatekv_kernel<<<cS, 256, 0, stream>>>(rhos, Wpe, gkv);
  prep_k_kernel<<<2048, 256, 0, stream>>>(Ek, gkv, x_idx, Khi, Klo);
  prep_vt_kernel<<<dim3(cS / 64, cD / 64, cB), 256, 0, stream>>>(Ev, gkv, x_idx, Vthi, Vtlo);
  qgate_ln_kernel<<<cB * cL, 256, 0, stream>>>(x_q, C_seq, Wpe, ln_q_g, ln_q_b, Yhi, Ylo);
  gemm_sp_kernel<1><<<dim3(8, 32), 256, 0, stream>>>(Yhi, Ylo, Wqhi, Wqlo, nullptr, qhi, qlo,
                                                     cB * cL, cD, cD, 0.125f);
  attn_mfma_kernel<<<dim3(cL / 64, cH, cB), 256, 0, stream>>>(qhi, qlo, Khi, Klo, Vthi, Vtlo,
                                                              AOhi, AOlo);
  gemm_sp_kernel<0><<<dim3(8, 32), 256, 0, stream>>>(AOhi, AOlo, Wohi, Wolo, out, nullptr,
                                                     nullptr, cB * cL, cD, cD, 1.f);
}